// Round 1
// 105.009 us; speedup vs baseline: 1.0034x; 1.0034x over previous
//
#include <hip/hip_runtime.h>
#include <stdint.h>

#define BQ 4
#define CC 3
#define MM 4096
#define NN 8192
#define KK 16
#define NP_OFF (BQ*CC*MM*KK)    // coords first, then indices
#define BLOCK 512
#define ROWS 32                  // queries per block (one 32-wide MFMA row tile)
#define CHUNK 1024               // points per LDS buffer (32 tiles of 32)
#define NCH (NN/CHUNK)           // 8
#define EPSA 4e-3f               // >= 2*E_split (E <= ~1.2e-3): superset guarantee

typedef __attribute__((ext_vector_type(8)))  short   short8;
typedef __attribute__((ext_vector_type(8)))  __bf16  bf16x8;
typedef __attribute__((ext_vector_type(16))) float   f32x16;
typedef unsigned int u32;
typedef unsigned short u16;

#define BT_PER_BATCH 256                 // 8192/32 point tiles
#define AT_PER_BATCH 128                 // 4096/32 query tiles
#define A_OFF (BQ*BT_PER_BATCH*64)       // 65536 short8 (B pack size)

__device__ __forceinline__ float rfl(float x) {
    return __uint_as_float((unsigned)__builtin_amdgcn_readfirstlane((int)__float_as_uint(x)));
}
// order-preserving float<->uint maps (monotone increasing)
__device__ __forceinline__ unsigned mapf(float f) {
    unsigned u = __float_as_uint(f);
    return (u & 0x80000000u) ? ~u : (u | 0x80000000u);
}
__device__ __forceinline__ float unmapf(unsigned u) {
    unsigned b = (u & 0x80000000u) ? (u & 0x7fffffffu) : ~u;
    return __uint_as_float(b);
}
// round-to-nearest-even bf16 (values here are O(1..40); no inf/nan concerns)
__device__ __forceinline__ u16 bfh(float f) {
    unsigned u = __float_as_uint(f);
    return (u16)((u + 0x7fffu + ((u >> 16) & 1u)) >> 16);
}
__device__ __forceinline__ float bff(u16 h) {
    return __uint_as_float(((unsigned)h) << 16);
}

__device__ __forceinline__ f32x16 mfma3216(short8 a, short8 b, f32x16 c) {
    return __builtin_amdgcn_mfma_f32_32x32x16_bf16(
        __builtin_bit_cast(bf16x8, a), __builtin_bit_cast(bf16x8, b), c, 0, 0, 0);
}

__device__ __forceinline__ void gl_lds16(const void* g, void* l) {
    __builtin_amdgcn_global_load_lds(
        (const __attribute__((address_space(1))) u32*)g,
        (__attribute__((address_space(3))) u32*)l, 16, 0, 0);
}

// ---------------------------------------------------------------------------
// Split-bf16 rank-11 encoding of dotf = q.p - 0.5*p2 in K=16 MFMA slots.
// A and B values are paired by (lane-half, element) position, so the sum is
// correct for any hw K-permutation shared by A and B (layouts are symmetric).
// term list (11 used slots):
//   xh*Xh  xl*Xh  xh*Xl | yh*Yh  yl*Yh  yh*Yl | zh*Zh  zl*Zh  zh*Zl | 1*Wh 1*Wl
// lane<32 carries elems {xh,xl/xh,xh/xl,yh, zh/zl,1/wh,1/wl,0}; lane>=32 the rest.
// ---------------------------------------------------------------------------
__global__ void pack_kernel(const float* __restrict__ query,
                            const float* __restrict__ points,
                            short8* __restrict__ ws)
{
    const int lane = threadIdx.x;        // 0..63
    const int bid  = blockIdx.x;
    const int hi   = lane >> 5;
    const int j    = lane & 31;
    short8 v = {0,0,0,0,0,0,0,0};
    if (bid < BQ*BT_PER_BATCH) {
        // ---- B pack: point tiles ----
        const int b = bid >> 8, tile = bid & 255;
        const int n = tile*32 + j;
        const float* pb = points + b*(CC*NN);
        float px = pb[n], py = pb[NN+n], pz = pb[2*NN+n];
        float pw = -0.5f*(px*px + py*py + pz*pz);
        u16 xh=bfh(px), yh=bfh(py), zh=bfh(pz), wh=bfh(pw);
        u16 xl=bfh(px-bff(xh)), yl=bfh(py-bff(yh)), zl=bfh(pz-bff(zh)), wl=bfh(pw-bff(wh));
        if (hi == 0) { v[0]=(short)xh; v[1]=(short)xh; v[2]=(short)xl; v[3]=(short)yh;
                       v[4]=(short)zl; v[5]=(short)wh; v[6]=(short)wl; v[7]=0; }
        else         { v[0]=(short)yh; v[1]=(short)yl; v[2]=(short)zh; v[3]=(short)zh; }
        ws[bid*64 + lane] = v;
    } else {
        // ---- A pack: query tiles ----
        const int t2 = bid - BQ*BT_PER_BATCH;     // 0..511
        const int b = t2 >> 7, rt = t2 & 127;
        const int m = rt*32 + j;
        const float* qb = query + b*(CC*MM);
        float qx = qb[m], qy = qb[MM+m], qz = qb[2*MM+m];
        u16 xh=bfh(qx), yh=bfh(qy), zh=bfh(qz);
        u16 xl=bfh(qx-bff(xh)), yl=bfh(qy-bff(yh)), zl=bfh(qz-bff(zh));
        const u16 ONE = 0x3F80u;
        if (hi == 0) { v[0]=(short)xh; v[1]=(short)xl; v[2]=(short)xh; v[3]=(short)yh;
                       v[4]=(short)zh; v[5]=(short)ONE; v[6]=(short)ONE; v[7]=0; }
        else         { v[0]=(short)yl; v[1]=(short)yh; v[2]=(short)zh; v[3]=(short)zl; }
        ws[A_OFF + t2*64 + lane] = v;
    }
}

__global__ __launch_bounds__(BLOCK, 4) void knn_kernel(
    const float* __restrict__ query,
    const float* __restrict__ points,
    const short8* __restrict__ ws,
    float* __restrict__ out)
{
    __shared__ short8 bpk[2][2048];      // 64 KB: dbuf of 32 packed tiles (1KB/tile)
    __shared__ unsigned aux[ROWS][64];   // 8 KB: slot-max (mapped), then candidates
    __shared__ unsigned scnt[ROWS];
    __shared__ unsigned rcbits[ROWS];

    const int tid  = threadIdx.x;
    const int lane = tid & 63;
    const int wv   = tid >> 6;           // 0..7: wave owns tiles wv*4..wv*4+3 per chunk
    const int col  = lane & 31;          // MFMA C/D col (= point index within tile)
    const int hi4  = (lane >> 5) << 2;   // row offset from lane half (measured C/D map)
    const int bid  = blockIdx.x;         // 0..511
    const int b    = bid >> 7;
    const int rt   = bid & 127;
    const int rb   = rt * 32;

    const float* pb = points + b*(CC*NN);
    const float* qb = query  + b*(CC*MM);

    // zero slot-max array (2048 words) + counters
    #pragma unroll
    for (int i = 0; i < 4; ++i) ((unsigned*)aux)[i*BLOCK + tid] = 0u;
    if (tid < ROWS) scnt[tid] = 0u;

    // A fragment (one 32-row query tile, shared by all 8 waves)
    const short8 af = ws[A_OFF + (b*AT_PER_BATCH + rt)*64 + lane];
    const f32x16 zf = {0.f,0.f,0.f,0.f,0.f,0.f,0.f,0.f,
                       0.f,0.f,0.f,0.f,0.f,0.f,0.f,0.f};

    // running slot-max per output j, split by tile parity -> slot = n mod 64,
    // i.e. 64 slots of 128 points per row: identical statistics/proof as before
    // (16 distinct points >= tau; <=15 exceed d16 => tau <= d16).
    float rm0[16], rm1[16];
    #pragma unroll
    for (int j = 0; j < 16; ++j) { rm0[j] = -__builtin_inff(); rm1[j] = -__builtin_inff(); }

    const short8* Bb = ws + (size_t)b * (BT_PER_BATCH*64);

    // staging = pure DMA: packed global layout == linear LDS layout (m104-safe)
    auto stage = [&](int ch, int bi) {
        #pragma unroll
        for (int i = 0; i < 4; ++i) {
            int idx = i*BLOCK + tid;
            gl_lds16(&Bb[ch*2048 + idx], &bpk[bi][idx]);
        }
    };

    // pass 1: slot-max of approx dot via MFMA; tile pairs (p, p+2) share parity
    auto comp1 = [&](int bi) {
        #pragma unroll
        for (int p = 0; p < 2; ++p) {
            short8 b0 = bpk[bi][(wv*4 + p)*64 + lane];
            short8 b1 = bpk[bi][(wv*4 + p + 2)*64 + lane];
            f32x16 d0 = mfma3216(af, b0, zf);
            f32x16 d1 = mfma3216(af, b1, zf);
            #pragma unroll
            for (int j = 0; j < 16; ++j) {
                float t = fmaxf(d0[j], d1[j]);           // hopes for v_max3 fusion
                if (p == 0) rm0[j] = fmaxf(rm0[j], t);
                else        rm1[j] = fmaxf(rm1[j], t);
            }
        }
    };

    stage(0, 0);
    #pragma unroll 1
    for (int ch = 0; ch < NCH; ch += 2) {
        __syncthreads();                       // buf0(ch) ready (also covers init)
        if (ch + 1 < NCH) stage(ch + 1, 1);
        comp1(0);
        __syncthreads();                       // buf1 ready; buf0 reads done
        if (ch + 2 < NCH) stage(ch + 2, 0);
        if (ch + 1 < NCH) comp1(1);
    }

    // ---- selection: flush per-lane running maxes into 64 slots per row ----
    #pragma unroll
    for (int j = 0; j < 16; ++j) {
        int row = ((j & 3) + 8*(j >> 2)) + hi4;   // measured 32x32 C/D row map
        atomicMax(&aux[row][col],      mapf(rm0[j]));
        atomicMax(&aux[row][col + 32], mapf(rm1[j]));
    }
    __syncthreads();
    stage(0, 0);                               // prefetch pass-2 chunk 0 under sorts

    // owner wave wv sorts rows wv*4..wv*4+3; tau = 16th largest of 64 slot maxes
    #pragma unroll
    for (int rr = 0; rr < 4; ++rr) {
        int row = wv*4 + rr;
        unsigned v = aux[row][lane];
        #pragma unroll
        for (int k = 2; k <= 64; k <<= 1) {
            #pragma unroll
            for (int jj = k >> 1; jj > 0; jj >>= 1) {
                unsigned o = __shfl_xor(v, jj, 64);
                bool keepmin = (((lane & jj) == 0) == ((lane & k) == 0));
                v = keepmin ? (v < o ? v : o) : (v > o ? v : o);
            }
        }
        unsigned tb = __shfl(v, 48, 64);       // 16th largest of 64
        if (lane == 0) rcbits[row] = __float_as_uint(unmapf(tb) - EPSA);
    }
    __syncthreads();                           // rcbits ready; aux reads done

    float rcv[16];
    #pragma unroll
    for (int j = 0; j < 16; ++j)
        rcv[j] = __uint_as_float(rcbits[((j & 3) + 8*(j >> 2)) + hi4]);

    // ---- pass 2: recompute approx dot (identical MFMA => identical values),
    //      collect candidate indices into aux (slot-max data now dead) ----
    auto comp2 = [&](int ch, int bi) {
        #pragma unroll
        for (int p = 0; p < 2; ++p) {
            short8 b0 = bpk[bi][(wv*4 + p)*64 + lane];
            short8 b1 = bpk[bi][(wv*4 + p + 2)*64 + lane];
            f32x16 d0 = mfma3216(af, b0, zf);
            f32x16 d1 = mfma3216(af, b1, zf);
            unsigned n0 = (unsigned)(ch*CHUNK + (wv*4 + p)*32 + col);
            #pragma unroll
            for (int j = 0; j < 16; ++j) {
                float t = fmaxf(d0[j], d1[j]);
                if (t >= rcv[j]) {                        // rare (~20/row)
                    int row = ((j & 3) + 8*(j >> 2)) + hi4;
                    if (d0[j] >= rcv[j]) {
                        unsigned pos = atomicAdd(&scnt[row], 1u);
                        if (pos < 64u) aux[row][pos] = n0;
                    }
                    if (d1[j] >= rcv[j]) {
                        unsigned pos = atomicAdd(&scnt[row], 1u);
                        if (pos < 64u) aux[row][pos] = n0 + 64u;
                    }
                }
            }
        }
    };

    #pragma unroll 1
    for (int ch = 0; ch < NCH; ch += 2) {
        __syncthreads();
        if (ch + 1 < NCH) stage(ch + 1, 1);
        comp2(ch, 0);
        __syncthreads();
        if (ch + 2 < NCH) stage(ch + 2, 0);
        if (ch + 1 < NCH) comp2(ch + 1, 1);
    }
    __syncthreads();

    // ---- Epilogue: wave wv owns rows wv*4..wv*4+3; exact reference rounding
    //      recomputed per candidate (unchanged, validated in prior session) ----
    #pragma unroll 1
    for (int rr = 0; rr < 4; ++rr) {
        int row = wv*4 + rr;
        int m   = rb + row;
        float ex = rfl(qb[m]);
        float ey = rfl(qb[MM + m]);
        float ez = rfl(qb[2*MM + m]);
        float eq2 = rfl(__fadd_rn(__fadd_rn(__fmul_rn(ex,ex), __fmul_rn(ey,ey)),
                                  __fmul_rn(ez,ez)));
        unsigned c = scnt[row]; if (c > 64u) c = 64u;   // >=16 guaranteed
        unsigned kb = 0xffffffffu, id = 0xffffffffu;
        if (lane < (int)c) {
            id = aux[row][lane];
            float px = pb[id], py = pb[NN + id], pz = pb[2*NN + id];
            float p2 = __fadd_rn(__fadd_rn(__fmul_rn(px,px), __fmul_rn(py,py)),
                                 __fmul_rn(pz,pz));
            float dot = __builtin_fmaf(ez, pz,
                         __builtin_fmaf(ey, py, __fmul_rn(ex, px)));
            float d = __fsub_rn(__fadd_rn(eq2, p2), __fmul_rn(2.0f, dot));
            unsigned fb = __float_as_uint(d);
            kb = (fb & 0x80000000u) ? ~fb : (fb | 0x80000000u);
        }
        #pragma unroll
        for (int k = 2; k <= 64; k <<= 1) {
            #pragma unroll
            for (int j = k >> 1; j > 0; j >>= 1) {
                unsigned ok = __shfl_xor(kb, j, 64);
                unsigned oi = __shfl_xor(id, j, 64);
                bool takeMin  = (((lane & j) == 0) == ((lane & k) == 0));
                bool selfLess = (kb < ok) || (kb == ok && id < oi);
                if (selfLess != takeMin) { kb = ok; id = oi; }
            }
        }
        if (lane < KK) {
            int oi = (int)id;
            out[NP_OFF + (b * MM + m) * KK + lane] = (float)oi;
            out[((b * CC + 0) * MM + m) * KK + lane] = pb[oi];
            out[((b * CC + 1) * MM + m) * KK + lane] = pb[NN + oi];
            out[((b * CC + 2) * MM + m) * KK + lane] = pb[2*NN + oi];
        }
    }
}

extern "C" void kernel_launch(void* const* d_in, const int* in_sizes, int n_in,
                              void* d_out, int out_size, void* d_ws, size_t ws_size,
                              hipStream_t stream) {
    // d_in[0] = k (scalar, =16), d_in[1] = query f32 [4,3,4096],
    // d_in[2] = points f32 [4,3,8192]
    const float* query  = (const float*)d_in[1];
    const float* points = (const float*)d_in[2];
    float* out = (float*)d_out;
    short8* ws = (short8*)d_ws;   // 1.5 MB: B pack (1 MB) + A pack (0.5 MB)

    pack_kernel<<<dim3(BQ*BT_PER_BATCH + BQ*AT_PER_BATCH), dim3(64), 0, stream>>>(
        query, points, ws);
    knn_kernel<<<dim3(BQ * (MM / ROWS)), dim3(BLOCK), 0, stream>>>(
        query, points, ws, out);
}

// Round 2
// 98.475 us; speedup vs baseline: 1.0700x; 1.0664x over previous
//
#include <hip/hip_runtime.h>
#include <stdint.h>

#define BQ 4
#define CC 3
#define MM 4096
#define NN 8192
#define KK 16
#define NP_OFF (BQ*CC*MM*KK)    // coords first, then indices
#define BLOCK 512
#define ROWS 32                  // queries per block (one 32-wide MFMA row tile)
#define EPSA 4e-3f               // >= 2*E_split (E <= ~1.2e-3): superset guarantee

typedef __attribute__((ext_vector_type(8)))  short   short8;
typedef __attribute__((ext_vector_type(8)))  __bf16  bf16x8;
typedef __attribute__((ext_vector_type(16))) float   f32x16;
typedef unsigned int u32;
typedef unsigned short u16;

#define BT_PER_BATCH 256                 // 8192/32 point tiles
#define WTILES 32                        // tiles per wave (256 / 8 waves)

__device__ __forceinline__ float rfl(float x) {
    return __uint_as_float((unsigned)__builtin_amdgcn_readfirstlane((int)__float_as_uint(x)));
}
// order-preserving float<->uint maps (monotone increasing)
__device__ __forceinline__ unsigned mapf(float f) {
    unsigned u = __float_as_uint(f);
    return (u & 0x80000000u) ? ~u : (u | 0x80000000u);
}
__device__ __forceinline__ float unmapf(unsigned u) {
    unsigned b = (u & 0x80000000u) ? (u & 0x7fffffffu) : ~u;
    return __uint_as_float(b);
}
// round-to-nearest-even bf16 (values here are O(1..40); no inf/nan concerns)
__device__ __forceinline__ u16 bfh(float f) {
    unsigned u = __float_as_uint(f);
    return (u16)((u + 0x7fffu + ((u >> 16) & 1u)) >> 16);
}
__device__ __forceinline__ float bff(u16 h) {
    return __uint_as_float(((unsigned)h) << 16);
}

__device__ __forceinline__ f32x16 mfma3216(short8 a, short8 b, f32x16 c) {
    return __builtin_amdgcn_mfma_f32_32x32x16_bf16(
        __builtin_bit_cast(bf16x8, a), __builtin_bit_cast(bf16x8, b), c, 0, 0, 0);
}

// ---------------------------------------------------------------------------
// Split-bf16 rank-11 encoding of dotf = q.p - 0.5*p2 in K=16 MFMA slots.
// A and B values are paired by (lane-half, element) position, so the sum is
// correct for any hw K-permutation shared by A and B (layouts are symmetric).
// term list (11 used slots):
//   xh*Xh  xl*Xh  xh*Xl | yh*Yh  yl*Yh  yh*Yl | zh*Zh  zl*Zh  zh*Zl | 1*Wh 1*Wl
// lane<32 carries elems {xh,xl/xh,xh/xl,yh, zh/zl,1/wh,1/wl,0}; lane>=32 rest.
// ---------------------------------------------------------------------------
__global__ void pack_kernel(const float* __restrict__ points,
                            short8* __restrict__ ws)
{
    const int g = blockIdx.x * 256 + threadIdx.x;  // 0..65535
    const int lane = g & 63;
    const int tileIdx = g >> 6;                    // 0..1023
    const int b = tileIdx >> 8, tile = tileIdx & 255;
    const int hi = lane >> 5;
    const int j = lane & 31;
    const int n = tile*32 + j;
    const float* pb = points + b*(CC*NN);
    float px = pb[n], py = pb[NN+n], pz = pb[2*NN+n];
    float pw = -0.5f*(px*px + py*py + pz*pz);
    u16 xh=bfh(px), yh=bfh(py), zh=bfh(pz), wh=bfh(pw);
    u16 xl=bfh(px-bff(xh)), yl=bfh(py-bff(yh)), zl=bfh(pz-bff(zh)), wl=bfh(pw-bff(wh));
    short8 v = {0,0,0,0,0,0,0,0};
    if (hi == 0) { v[0]=(short)xh; v[1]=(short)xh; v[2]=(short)xl; v[3]=(short)yh;
                   v[4]=(short)zl; v[5]=(short)wh; v[6]=(short)wl; v[7]=0; }
    else         { v[0]=(short)yh; v[1]=(short)yl; v[2]=(short)zh; v[3]=(short)zh; }
    ws[tileIdx*64 + lane] = v;
}

__global__ __launch_bounds__(BLOCK, 4) void knn_kernel(
    const float* __restrict__ query,
    const float* __restrict__ points,
    const short8* __restrict__ ws,
    float* __restrict__ out)
{
    __shared__ unsigned aux[ROWS][64];   // 8 KB: slot-max (mapped), then candidates
    __shared__ unsigned scnt[ROWS];
    __shared__ unsigned rcbits[ROWS];

    const int tid  = threadIdx.x;
    const int lane = tid & 63;
    const int wv   = tid >> 6;           // 0..7: wave owns tiles wv*32..wv*32+31
    const int col  = lane & 31;          // MFMA C/D col (= point index within tile)
    const int hi4  = (lane >> 5) << 2;   // row offset from lane half (measured C/D map)
    // XCD swizzle: pin each batch's 256 KB B-pack to a 2-XCD pair (L2 locality)
    const int bid  = blockIdx.x;         // 0..511
    const int lid  = ((bid & 7) << 6) | (bid >> 3);
    const int b    = lid >> 7;
    const int rt   = lid & 127;
    const int rb   = rt * 32;

    const float* pb = points + b*(CC*NN);
    const float* qb = query  + b*(CC*MM);

    // zero slot-max array (2048 words) + counters
    #pragma unroll
    for (int i = 0; i < 4; ++i) ((unsigned*)aux)[i*BLOCK + tid] = 0u;
    if (tid < ROWS) scnt[tid] = 0u;

    // ---- A fragment packed in-kernel (af depends only on lane; one tile/block)
    {
    }
    const int jq = lane & 31, hiq = lane >> 5;
    const int mA = rb + jq;
    float qxv = qb[mA], qyv = qb[MM+mA], qzv = qb[2*MM+mA];
    u16 axh=bfh(qxv), ayh=bfh(qyv), azh=bfh(qzv);
    u16 axl=bfh(qxv-bff(axh)), ayl=bfh(qyv-bff(ayh)), azl=bfh(qzv-bff(azh));
    const u16 ONE = 0x3F80u;
    short8 af = {0,0,0,0,0,0,0,0};
    if (hiq == 0) { af[0]=(short)axh; af[1]=(short)axl; af[2]=(short)axh; af[3]=(short)ayh;
                    af[4]=(short)azh; af[5]=(short)ONE; af[6]=(short)ONE; }
    else          { af[0]=(short)ayl; af[1]=(short)ayh; af[2]=(short)azh; af[3]=(short)azl; }

    const f32x16 zf = {0.f,0.f,0.f,0.f,0.f,0.f,0.f,0.f,
                       0.f,0.f,0.f,0.f,0.f,0.f,0.f,0.f};

    __syncthreads();                       // aux/scnt zeroed before any atomic

    // running slot-max per output j, split by tile parity -> slot = n mod 64,
    // i.e. 64 slots of 128 points per row: identical statistics/proof as before
    // (16 distinct points >= tau; <=15 exceed d16 => tau <= d16).
    float rm0[16], rm1[16];
    #pragma unroll
    for (int j = 0; j < 16; ++j) { rm0[j] = -__builtin_inff(); rm1[j] = -__builtin_inff(); }

    // ---- Pass 1: stream own 32 tiles straight from L2, no LDS, no barriers --
    {
        const short8* Wp = ws + ((size_t)b*BT_PER_BATCH + wv*WTILES)*64 + lane;
        #pragma unroll 1
        for (int it = 0; it < 8; ++it) {
            short8 b0 = Wp[0*64];          // tiles 4it+0..3: imm offsets 0..3072B
            short8 b1 = Wp[1*64];
            short8 b2 = Wp[2*64];
            short8 b3 = Wp[3*64];
            f32x16 d0 = mfma3216(af, b0, zf);
            f32x16 d2 = mfma3216(af, b2, zf);
            f32x16 d1 = mfma3216(af, b1, zf);
            f32x16 d3 = mfma3216(af, b3, zf);
            #pragma unroll
            for (int j = 0; j < 16; ++j) {   // even tiles -> rm0, odd -> rm1 (v_max3)
                rm0[j] = fmaxf(rm0[j], fmaxf(d0[j], d2[j]));
                rm1[j] = fmaxf(rm1[j], fmaxf(d1[j], d3[j]));
            }
            Wp += 4*64;
        }
    }

    // ---- selection: flush per-lane running maxes into 64 slots per row ----
    #pragma unroll
    for (int j = 0; j < 16; ++j) {
        int row = ((j & 3) + 8*(j >> 2)) + hi4;   // measured 32x32 C/D row map
        atomicMax(&aux[row][col],      mapf(rm0[j]));
        atomicMax(&aux[row][col + 32], mapf(rm1[j]));
    }
    __syncthreads();

    // owner wave wv sorts rows wv*4..wv*4+3; tau = 16th largest of 64 slot maxes
    #pragma unroll
    for (int rr = 0; rr < 4; ++rr) {
        int row = wv*4 + rr;
        unsigned v = aux[row][lane];
        #pragma unroll
        for (int k = 2; k <= 64; k <<= 1) {
            #pragma unroll
            for (int jj = k >> 1; jj > 0; jj >>= 1) {
                unsigned o = __shfl_xor(v, jj, 64);
                bool keepmin = (((lane & jj) == 0) == ((lane & k) == 0));
                v = keepmin ? (v < o ? v : o) : (v > o ? v : o);
            }
        }
        unsigned tb = __shfl(v, 48, 64);       // 16th largest of 64
        if (lane == 0) rcbits[row] = __float_as_uint(unmapf(tb) - EPSA);
    }
    __syncthreads();                           // rcbits ready; aux reads done

    float rcv[16];
    #pragma unroll
    for (int j = 0; j < 16; ++j)
        rcv[j] = __uint_as_float(rcbits[((j & 3) + 8*(j >> 2)) + hi4]);

    // ---- Pass 2: recompute approx dot (identical MFMA => identical values),
    //      collect candidate indices into aux (slot-max data now dead) ----
    {
        const short8* Wp = ws + ((size_t)b*BT_PER_BATCH + wv*WTILES)*64 + lane;
        unsigned nbase = (unsigned)(wv*WTILES*32 + col);
        #pragma unroll 1
        for (int it = 0; it < 8; ++it) {
            short8 b0 = Wp[0*64];
            short8 b1 = Wp[1*64];
            short8 b2 = Wp[2*64];
            short8 b3 = Wp[3*64];
            f32x16 d0 = mfma3216(af, b0, zf);
            f32x16 d1 = mfma3216(af, b1, zf);
            f32x16 d2 = mfma3216(af, b2, zf);
            f32x16 d3 = mfma3216(af, b3, zf);
            #pragma unroll
            for (int j = 0; j < 16; ++j) {
                float tm = fmaxf(fmaxf(d0[j], d1[j]), fmaxf(d2[j], d3[j]));
                if (tm >= rcv[j]) {                       // rare (~20/row total)
                    int row = ((j & 3) + 8*(j >> 2)) + hi4;
                    if (d0[j] >= rcv[j]) {
                        unsigned pos = atomicAdd(&scnt[row], 1u);
                        if (pos < 64u) aux[row][pos] = nbase;
                    }
                    if (d1[j] >= rcv[j]) {
                        unsigned pos = atomicAdd(&scnt[row], 1u);
                        if (pos < 64u) aux[row][pos] = nbase + 32u;
                    }
                    if (d2[j] >= rcv[j]) {
                        unsigned pos = atomicAdd(&scnt[row], 1u);
                        if (pos < 64u) aux[row][pos] = nbase + 64u;
                    }
                    if (d3[j] >= rcv[j]) {
                        unsigned pos = atomicAdd(&scnt[row], 1u);
                        if (pos < 64u) aux[row][pos] = nbase + 96u;
                    }
                }
            }
            Wp += 4*64;
            nbase += 128u;
        }
    }
    __syncthreads();

    // ---- Epilogue: wave wv owns rows wv*4..wv*4+3; exact reference rounding
    //      recomputed per candidate (unchanged, validated in prior rounds) ----
    #pragma unroll 1
    for (int rr = 0; rr < 4; ++rr) {
        int row = wv*4 + rr;
        int m   = rb + row;
        float ex = rfl(qb[m]);
        float ey = rfl(qb[MM + m]);
        float ez = rfl(qb[2*MM + m]);
        float eq2 = rfl(__fadd_rn(__fadd_rn(__fmul_rn(ex,ex), __fmul_rn(ey,ey)),
                                  __fmul_rn(ez,ez)));
        unsigned c = scnt[row]; if (c > 64u) c = 64u;   // >=16 guaranteed
        unsigned kb = 0xffffffffu, id = 0xffffffffu;
        if (lane < (int)c) {
            id = aux[row][lane];
            float px = pb[id], py = pb[NN + id], pz = pb[2*NN + id];
            float p2 = __fadd_rn(__fadd_rn(__fmul_rn(px,px), __fmul_rn(py,py)),
                                 __fmul_rn(pz,pz));
            float dot = __builtin_fmaf(ez, pz,
                         __builtin_fmaf(ey, py, __fmul_rn(ex, px)));
            float d = __fsub_rn(__fadd_rn(eq2, p2), __fmul_rn(2.0f, dot));
            unsigned fb = __float_as_uint(d);
            kb = (fb & 0x80000000u) ? ~fb : (fb | 0x80000000u);
        }
        #pragma unroll
        for (int k = 2; k <= 64; k <<= 1) {
            #pragma unroll
            for (int j = k >> 1; j > 0; j >>= 1) {
                unsigned ok = __shfl_xor(kb, j, 64);
                unsigned oi = __shfl_xor(id, j, 64);
                bool takeMin  = (((lane & j) == 0) == ((lane & k) == 0));
                bool selfLess = (kb < ok) || (kb == ok && id < oi);
                if (selfLess != takeMin) { kb = ok; id = oi; }
            }
        }
        if (lane < KK) {
            int oi = (int)id;
            out[NP_OFF + (b * MM + m) * KK + lane] = (float)oi;
            out[((b * CC + 0) * MM + m) * KK + lane] = pb[oi];
            out[((b * CC + 1) * MM + m) * KK + lane] = pb[NN + oi];
            out[((b * CC + 2) * MM + m) * KK + lane] = pb[2*NN + oi];
        }
    }
}

extern "C" void kernel_launch(void* const* d_in, const int* in_sizes, int n_in,
                              void* d_out, int out_size, void* d_ws, size_t ws_size,
                              hipStream_t stream) {
    // d_in[0] = k (scalar, =16), d_in[1] = query f32 [4,3,4096],
    // d_in[2] = points f32 [4,3,8192]
    const float* query  = (const float*)d_in[1];
    const float* points = (const float*)d_in[2];
    float* out = (float*)d_out;
    short8* ws = (short8*)d_ws;   // 1 MB: packed B (4 batches x 256 tiles x 1 KB)

    pack_kernel<<<dim3(256), dim3(256), 0, stream>>>(points, ws);
    knn_kernel<<<dim3(BQ * (MM / ROWS)), dim3(BLOCK), 0, stream>>>(
        query, points, ws, out);
}